// Round 1
// baseline (113.276 us; speedup 1.0000x reference)
//
#include <hip/hip_runtime.h>

// Input: (2, 1, 256, 256, 256) float32. x = inputs[:,0] -> (2,256,256,256).
// core = x[:, :255, :255, :255]
// dd = (core - x[:,1:,:255,:255]) * 256
// dh = (core - x[:,:255,1:,:255]) * 256
// dw = (core - x[:,:255,:255,1:]) * 256
// out = mean(|sqrt(dd^2+dh^2+dw^2) - 1|)   -- scalar f32

#define DVOL 256
#define CORE 255

__global__ void eik_partial(const float* __restrict__ x, float* __restrict__ part) {
    const int blk = blockIdx.x;
    const int b   = blk / (CORE * CORE);
    const int rem = blk % (CORE * CORE);
    const int d   = rem / CORE;
    const int h   = rem % CORE;
    const int tid = threadIdx.x;

    const long long base = (long long)b * (DVOL * DVOL * DVOL)
                         + (long long)d * (DVOL * DVOL)
                         + (long long)h * DVOL;

    float val = 0.0f;
    if (tid < CORE) {
        float c  = x[base + tid];
        float xd = x[base + DVOL * DVOL + tid];  // d+1
        float xh = x[base + DVOL + tid];         // h+1
        float xw = x[base + tid + 1];            // w+1
        float dd = (c - xd) * 256.0f;
        float dh = (c - xh) * 256.0f;
        float dw = (c - xw) * 256.0f;
        float n  = sqrtf(dd * dd + dh * dh + dw * dw);
        val = fabsf(n - 1.0f);
    }

    // wave (64-lane) shuffle reduction
    #pragma unroll
    for (int off = 32; off > 0; off >>= 1)
        val += __shfl_down(val, off, 64);

    __shared__ float wsum[4];
    const int wave = tid >> 6;
    if ((tid & 63) == 0) wsum[wave] = val;
    __syncthreads();
    if (tid == 0)
        part[blk] = wsum[0] + wsum[1] + wsum[2] + wsum[3];
}

__global__ void eik_final(const float* __restrict__ part, float* __restrict__ out, int n) {
    const int tid = threadIdx.x;
    double s = 0.0;
    for (int i = tid; i < n; i += 1024)
        s += (double)part[i];

    __shared__ double sm[1024];
    sm[tid] = s;
    __syncthreads();
    #pragma unroll
    for (int off = 512; off > 0; off >>= 1) {
        if (tid < off) sm[tid] += sm[tid + off];
        __syncthreads();
    }
    if (tid == 0) {
        const double N = 2.0 * CORE * CORE * CORE;  // 33,162,750
        out[0] = (float)(sm[0] / N);
    }
}

extern "C" void kernel_launch(void* const* d_in, const int* in_sizes, int n_in,
                              void* d_out, int out_size, void* d_ws, size_t ws_size,
                              hipStream_t stream) {
    const float* x = (const float*)d_in[0];
    float* out = (float*)d_out;
    float* part = (float*)d_ws;  // 2*255*255 = 130050 floats = 520 KB

    const int nblocks = 2 * CORE * CORE;  // 130050
    eik_partial<<<nblocks, 256, 0, stream>>>(x, part);
    eik_final<<<1, 1024, 0, stream>>>(part, out, nblocks);
}

// Round 2
// 40.836 us; speedup vs baseline: 2.7739x; 2.7739x over previous
//
#include <hip/hip_runtime.h>

// Input: (2, 1, 256, 256, 256) float32. x = inputs[:,0] -> (2,256,256,256).
// dd = (core - x[d+1]) * 256 ; dh = (core - x[h+1]) * 256 ; dw = (core - x[w+1]) * 256
// out = mean(|sqrt(dd^2+dh^2+dw^2) - 1|) over 2*255^3 core elements.
//
// Strategy: wave-per-row pencil. Each 64-lane wave owns (b, h), walks DCHUNK
// d-planes. Self row carried in registers (d+1 load becomes next iter's self).
// h+1 row of wave w == wave w+1's row loaded a step earlier -> L1 hit.
// w+1 shift handled in-register + one __shfl_down.

#define DVOL 256
#define PLANE (DVOL * DVOL)
#define CORE 255
#define DCHUNK 32
#define NBLOCKS 1024  // 2 b * 64 h-groups * 8 d-chunks

__global__ __launch_bounds__(256) void eik_partial(const float* __restrict__ x,
                                                   float* __restrict__ part) {
    const int tid  = threadIdx.x;
    const int lane = tid & 63;
    const int wave = tid >> 6;

    const int blk = blockIdx.x;
    const int dc = blk & 7;          // d-chunk
    const int hg = (blk >> 3) & 63;  // h-group of 4
    const int b  = blk >> 9;         // batch

    const int h  = hg * 4 + wave;
    const int d0 = dc * DCHUNK;
    const int dend = min(d0 + DCHUNK, CORE);

    float acc = 0.0f;

    if (h < CORE) {
        const float* rowp = x + (long long)b * (DVOL * PLANE)
                              + (long long)d0 * PLANE
                              + (long long)h * DVOL
                              + lane * 4;
        float4 c = *(const float4*)rowp;  // self row, plane d0

        for (int d = d0; d < dend; ++d) {
            const float4 cd = *(const float4*)(rowp + PLANE);  // plane d+1
            const float4 ch = *(const float4*)(rowp + DVOL);   // row h+1
            const float nx = __shfl_down(c.x, 1, 64);          // lane+1's first elem

            {
                const float a0 = c.x - cd.x, b0 = c.x - ch.x, w0 = c.x - c.y;
                const float s = a0 * a0 + b0 * b0 + w0 * w0;
                acc += fabsf(256.0f * sqrtf(s) - 1.0f);
            }
            {
                const float a0 = c.y - cd.y, b0 = c.y - ch.y, w0 = c.y - c.z;
                const float s = a0 * a0 + b0 * b0 + w0 * w0;
                acc += fabsf(256.0f * sqrtf(s) - 1.0f);
            }
            {
                const float a0 = c.z - cd.z, b0 = c.z - ch.z, w0 = c.z - c.w;
                const float s = a0 * a0 + b0 * b0 + w0 * w0;
                acc += fabsf(256.0f * sqrtf(s) - 1.0f);
            }
            if (lane != 63) {  // w=255 is not core
                const float a0 = c.w - cd.w, b0 = c.w - ch.w, w0 = c.w - nx;
                const float s = a0 * a0 + b0 * b0 + w0 * w0;
                acc += fabsf(256.0f * sqrtf(s) - 1.0f);
            }

            c = cd;
            rowp += PLANE;
        }
    }

    // wave shuffle reduction
    #pragma unroll
    for (int off = 32; off > 0; off >>= 1)
        acc += __shfl_down(acc, off, 64);

    __shared__ float wsum[4];
    if (lane == 0) wsum[wave] = acc;
    __syncthreads();
    if (tid == 0)
        part[blk] = wsum[0] + wsum[1] + wsum[2] + wsum[3];
}

__global__ void eik_final(const float* __restrict__ part, float* __restrict__ out) {
    const int tid = threadIdx.x;
    double s = (double)part[tid] + (double)part[tid + 256]
             + (double)part[tid + 512] + (double)part[tid + 768];

    __shared__ double sm[256];
    sm[tid] = s;
    __syncthreads();
    #pragma unroll
    for (int off = 128; off > 0; off >>= 1) {
        if (tid < off) sm[tid] += sm[tid + off];
        __syncthreads();
    }
    if (tid == 0) {
        const double N = 2.0 * CORE * CORE * CORE;  // 33,162,750
        out[0] = (float)(sm[0] / N);
    }
}

extern "C" void kernel_launch(void* const* d_in, const int* in_sizes, int n_in,
                              void* d_out, int out_size, void* d_ws, size_t ws_size,
                              hipStream_t stream) {
    const float* x = (const float*)d_in[0];
    float* out = (float*)d_out;
    float* part = (float*)d_ws;  // 1024 floats = 4 KB

    eik_partial<<<NBLOCKS, 256, 0, stream>>>(x, part);
    eik_final<<<1, 256, 0, stream>>>(part, out);
}

// Round 3
// 33.248 us; speedup vs baseline: 3.4070x; 1.2282x over previous
//
#include <hip/hip_runtime.h>

// Input: (2, 1, 256, 256, 256) float32. x = inputs[:,0] -> (2,256,256,256).
// dd = (core - x[d+1]) * 256 ; dh = (core - x[h+1]) * 256 ; dw = (core - x[w+1]) * 256
// out = mean(|sqrt(dd^2+dh^2+dw^2) - 1|) over 2*255^3 core elements.
// Note 256 = 2^8 factors exactly out of the sqrt: |256*sqrt(s)-1| bit-exact.
//
// Strategy: 4-row register pencil per wave. Wave carries rows h..h+3 of plane d
// in registers; per iteration loads 4 rows of plane d+1 (become next self) +
// 1 boundary row (h+4, plane d), computes 16 outputs. Loads/output = 0.31.
// Block = 4 waves covering 16 contiguous h rows (boundary row is neighbor
// wave's register row -> L1 co-resident).

#define DVOL 256
#define PLANE (DVOL * DVOL)
#define CORE 255

__device__ __forceinline__ float sq(float v) { return v * v; }

__device__ __forceinline__ float row_term(const float4 c, const float4 h1,
                                          const float4 d1, int lane, bool valid) {
    const float nx = __shfl_down(c.x, 1, 64);  // lane+1's first element
    if (!valid) return 0.0f;
    float acc;
    float s;
    s = sq(c.x - d1.x) + sq(c.x - h1.x) + sq(c.x - c.y);
    acc = fabsf(fmaf(256.0f, sqrtf(s), -1.0f));
    s = sq(c.y - d1.y) + sq(c.y - h1.y) + sq(c.y - c.z);
    acc += fabsf(fmaf(256.0f, sqrtf(s), -1.0f));
    s = sq(c.z - d1.z) + sq(c.z - h1.z) + sq(c.z - c.w);
    acc += fabsf(fmaf(256.0f, sqrtf(s), -1.0f));
    if (lane != 63) {  // w = lane*4+3 = 255 is not core
        s = sq(c.w - d1.w) + sq(c.w - h1.w) + sq(c.w - nx);
        acc += fabsf(fmaf(256.0f, sqrtf(s), -1.0f));
    }
    return acc;
}

__global__ __launch_bounds__(256) void eik_partial(const float* __restrict__ x,
                                                   float* __restrict__ part) {
    const int tid  = threadIdx.x;
    const int lane = tid & 63;
    const int wave = tid >> 6;

    const int blk = blockIdx.x;          // [0, 1024)
    const int b   = blk >> 9;            // batch
    const int dc  = (blk >> 4) & 31;     // d-chunk (8 planes each)
    const int hg  = (blk & 15) * 4 + wave;  // h-group [0,64), 4 rows each
    const int h   = hg * 4;              // first row: 0..252
    const int d0  = dc * 8;
    const int dend = min(d0 + 8, CORE);  // last chunk: 7 planes
    const bool row3_valid = (h + 3 < CORE);  // hg<63: row 255 is not core
    const int ch_off = (h + 4 < DVOL) ? 4 * DVOL : 3 * DVOL;  // clamp (unused when invalid... only row3 uses ch)

    const float* base = x + (long long)b * (DVOL * PLANE)
                          + (long long)d0 * PLANE
                          + (long long)h * DVOL
                          + lane * 4;

    float4 r0 = *(const float4*)(base);
    float4 r1 = *(const float4*)(base + DVOL);
    float4 r2 = *(const float4*)(base + 2 * DVOL);
    float4 r3 = *(const float4*)(base + 3 * DVOL);

    float acc = 0.0f;
    for (int d = d0; d < dend; ++d) {
        const float4 cd0 = *(const float4*)(base + PLANE);
        const float4 cd1 = *(const float4*)(base + PLANE + DVOL);
        const float4 cd2 = *(const float4*)(base + PLANE + 2 * DVOL);
        const float4 cd3 = *(const float4*)(base + PLANE + 3 * DVOL);
        const float4 ch  = *(const float4*)(base + ch_off);  // row h+4, plane d

        acc += row_term(r0, r1, cd0, lane, true);
        acc += row_term(r1, r2, cd1, lane, true);
        acc += row_term(r2, r3, cd2, lane, true);
        acc += row_term(r3, ch, cd3, lane, row3_valid);

        r0 = cd0; r1 = cd1; r2 = cd2; r3 = cd3;
        base += PLANE;
    }

    // wave shuffle reduction
    #pragma unroll
    for (int off = 32; off > 0; off >>= 1)
        acc += __shfl_down(acc, off, 64);

    __shared__ float wsum[4];
    if (lane == 0) wsum[wave] = acc;
    __syncthreads();
    if (tid == 0)
        part[blk] = wsum[0] + wsum[1] + wsum[2] + wsum[3];
}

__global__ void eik_final(const float* __restrict__ part, float* __restrict__ out) {
    const int tid = threadIdx.x;
    double s = (double)part[tid] + (double)part[tid + 256]
             + (double)part[tid + 512] + (double)part[tid + 768];

    __shared__ double sm[256];
    sm[tid] = s;
    __syncthreads();
    #pragma unroll
    for (int off = 128; off > 0; off >>= 1) {
        if (tid < off) sm[tid] += sm[tid + off];
        __syncthreads();
    }
    if (tid == 0) {
        const double N = 2.0 * CORE * CORE * CORE;  // 33,162,750
        out[0] = (float)(sm[0] / N);
    }
}

extern "C" void kernel_launch(void* const* d_in, const int* in_sizes, int n_in,
                              void* d_out, int out_size, void* d_ws, size_t ws_size,
                              hipStream_t stream) {
    const float* x = (const float*)d_in[0];
    float* out = (float*)d_out;
    float* part = (float*)d_ws;  // 1024 floats = 4 KB

    eik_partial<<<1024, 256, 0, stream>>>(x, part);
    eik_final<<<1, 256, 0, stream>>>(part, out);
}